// Round 4
// baseline (312.133 us; speedup 1.0000x reference)
//
#include <hip/hip_runtime.h>
#include <math.h>

#define NB 2
#define NN 2048
#define DD 512

typedef __attribute__((ext_vector_type(8))) short short8;
typedef __attribute__((ext_vector_type(4))) float f32x4;

__device__ __forceinline__ unsigned short f2bf(float x) {
  union { float f; unsigned u; } a;
  a.f = x;
  unsigned r = a.u + 0x7FFF + ((a.u >> 16) & 1);  // RNE
  return (unsigned short)(r >> 16);
}
__device__ __forceinline__ float bf2f(unsigned short u) {
  union { unsigned u; float f; } a;
  a.u = ((unsigned)u) << 16;
  return a.f;
}

__device__ __forceinline__ float waveReduceSum(float v) {
#pragma unroll
  for (int o = 32; o; o >>= 1) v += __shfl_down(v, o, 64);
  return v;
}
__device__ __forceinline__ float blockReduceSum(float v, float* red4) {
  int tid = threadIdx.x;
  __syncthreads();
  v = waveReduceSum(v);
  if ((tid & 63) == 0) red4[tid >> 6] = v;
  __syncthreads();
  return red4[0] + red4[1] + red4[2] + red4[3];
}

// ---------------- LayerNorm -> bf16: one block (256 thr) per row of 512 --------
__global__ __launch_bounds__(256) void ln_kernel(const float* __restrict__ x,
                                                 const float* __restrict__ g,
                                                 const float* __restrict__ bb,
                                                 unsigned short* __restrict__ y) {
  int row = blockIdx.x;
  int t = threadIdx.x;
  const float* xr = x + (size_t)row * DD;
  __shared__ float red4[4];
  float2 v = *(const float2*)&xr[2 * t];
  float s = blockReduceSum(v.x + v.y, red4);
  float mu = s * (1.0f / 512.0f);
  float d0 = v.x - mu, d1 = v.y - mu;
  float ss = blockReduceSum(d0 * d0 + d1 * d1, red4);
  float rstd = rsqrtf(ss * (1.0f / 512.0f) + 1e-6f);
  float2 gg = *(const float2*)&g[2 * t];
  float2 bv = *(const float2*)&bb[2 * t];
  ushort2 o;
  o.x = f2bf(d0 * rstd * gg.x + bv.x);
  o.y = f2bf(d1 * rstd * gg.y + bv.y);
  *(ushort2*)&y[(size_t)row * DD + 2 * t] = o;
}

// ---------------- W [512k][512c] fp32 -> WT [c][k] bf16 ------------------------
__global__ __launch_bounds__(256) void wt_kernel(const float* __restrict__ W,
                                                 unsigned short* __restrict__ WT) {
  __shared__ float tile[64][65];
  int kt = blockIdx.x * 64, ct = blockIdx.y * 64;
  int t = threadIdx.x;
#pragma unroll
  for (int u = 0; u < 16; u++) {
    int lin = t + u * 256;
    int kl = lin >> 6, cl = lin & 63;
    tile[kl][cl] = W[(size_t)(kt + kl) * DD + ct + cl];
  }
  __syncthreads();
#pragma unroll
  for (int u = 0; u < 16; u++) {
    int lin = t + u * 256;
    int cl = lin >> 6, kl = lin & 63;
    WT[(size_t)(ct + cl) * DD + kt + kl] = f2bf(tile[kl][cl]);
  }
}

// ---------------- v = W @ a  (per head): vs/vd are [H][512] fp32 ---------------
__global__ __launch_bounds__(256) void v_kernel(const float* __restrict__ W,
                                                const float* __restrict__ asrc,
                                                const float* __restrict__ adst,
                                                float* __restrict__ vs,
                                                float* __restrict__ vd, int HN, int Dh) {
  int t = threadIdx.x;
  int dl = t >> 2, kq = t & 3;
  int d = blockIdx.x * 64 + dl;
  int kn = Dh >> 2;
  for (int h = 0; h < HN; h++) {
    const float* wr = W + (size_t)d * DD + h * Dh + kq * kn;
    const float* as = asrc + h * Dh + kq * kn;
    const float* ad = adst + h * Dh + kq * kn;
    float s = 0.f, dd2 = 0.f;
    for (int k = 0; k < kn; k++) {
      float wv = wr[k];
      s += wv * as[k];
      dd2 += wv * ad[k];
    }
    s += __shfl_xor(s, 1);
    s += __shfl_xor(s, 2);
    dd2 += __shfl_xor(dd2, 1);
    dd2 += __shfl_xor(dd2, 2);
    if (kq == 0) {
      vs[(size_t)h * DD + d] = s;
      vd[(size_t)h * DD + d] = dd2;
    }
  }
}

// ---------------- bf16 MFMA GEMM, K-split: hbT[b][c][j] = bf16( lnB @ W ) ------
// Block: out tile 16 rows x 64 cols; wave w owns K in [w*128, w*128+128).
// Partial accumulators merged through LDS.
__global__ __launch_bounds__(256) void gemm_kernel(const unsigned short* __restrict__ A,
                                                   const unsigned short* __restrict__ BT,
                                                   unsigned short* __restrict__ hbT) {
  __shared__ float accL[4][16][65];
  int t = threadIdx.x, w = t >> 6, l = t & 63;
  int li = l & 15, lg = l >> 4;
  int R0 = blockIdx.x * 16;  // global row (b*NN + j)
  int c0 = blockIdx.y * 64;
  const unsigned short* ar = A + (size_t)(R0 + li) * DD + w * 128 + lg * 8;
  const unsigned short* br = BT + (size_t)(c0 + li) * DD + w * 128 + lg * 8;
  f32x4 acc[4] = {};
#pragma unroll
  for (int k0 = 0; k0 < 128; k0 += 32) {
    short8 af = *(const short8*)(ar + k0);
#pragma unroll
    for (int f = 0; f < 4; f++) {
      short8 bf = *(const short8*)(br + (size_t)f * 16 * DD + k0);
      acc[f] = __builtin_amdgcn_mfma_f32_16x16x32_bf16(af, bf, acc[f], 0, 0, 0);
    }
  }
#pragma unroll
  for (int f = 0; f < 4; f++)
#pragma unroll
    for (int r = 0; r < 4; r++) accL[w][lg * 4 + r][f * 16 + li] = acc[f][r];
  __syncthreads();
  int b = R0 >> 11, j0 = R0 & (NN - 1);
#pragma unroll
  for (int u = 0; u < 4; u++) {
    int idx = t + u * 256;  // 1024 outputs: c = idx>>4, r = idx&15
    int c = idx >> 4, r = idx & 15;
    float v = accL[0][r][c] + accL[1][r][c] + accL[2][r][c] + accL[3][r][c];
    hbT[((size_t)b * DD + c0 + c) * NN + j0 + r] = f2bf(v);
  }
}

// ---------------- s,t: wave per row; s = lnrow . vs[h], t = lnrow . vd[h] ------
__global__ __launch_bounds__(256) void st_kernel(const unsigned short* __restrict__ lnB,
                                                 const float* __restrict__ vs,
                                                 const float* __restrict__ vd,
                                                 float* __restrict__ sOut,
                                                 float* __restrict__ tOut, int HN) {
  int t = threadIdx.x, w = t >> 6, l = t & 63;
  int row = blockIdx.x * 4 + w;
  int b = row >> 11, n = row & (NN - 1);
  const unsigned short* lr = lnB + (size_t)row * DD + l * 8;
  union { short8 v; unsigned short u[8]; } xv;
  xv.v = *(const short8*)lr;
  float xf[8];
#pragma unroll
  for (int k = 0; k < 8; k++) xf[k] = bf2f(xv.u[k]);
  for (int h = 0; h < HN; h++) {
    const float* vsr = vs + (size_t)h * DD + l * 8;
    const float* vdr = vd + (size_t)h * DD + l * 8;
    float4 a0 = *(const float4*)vsr, a1 = *(const float4*)(vsr + 4);
    float4 c0 = *(const float4*)vdr, c1 = *(const float4*)(vdr + 4);
    float ps = xf[0] * a0.x + xf[1] * a0.y + xf[2] * a0.z + xf[3] * a0.w +
               xf[4] * a1.x + xf[5] * a1.y + xf[6] * a1.z + xf[7] * a1.w;
    float pd = xf[0] * c0.x + xf[1] * c0.y + xf[2] * c0.z + xf[3] * c0.w +
               xf[4] * c1.x + xf[5] * c1.y + xf[6] * c1.z + xf[7] * c1.w;
#pragma unroll
    for (int o = 32; o; o >>= 1) {
      ps += __shfl_xor(ps, o);
      pd += __shfl_xor(pd, o);
    }
    if (l == 0) {
      sOut[((size_t)b * HN + h) * NN + n] = ps;
      tOut[((size_t)b * HN + h) * NN + n] = pd;
    }
  }
}

// ---------------- fused flash-style PV with intra-block j-split ----------------
// Block: out tile 16 rows x 64 cols; wave w processes j in [w*NN/4, (w+1)*NN/4)
// with independent online-softmax state; merge (m, sum, O-partial) via LDS.
// Lane l computes P[row=l&15][j=(l>>4)*8..+8] straight into the MFMA A-fragment.
template <int HN>
__global__ __launch_bounds__(256) void pv_kernel(const unsigned short* __restrict__ hbT,
                                                 const float* __restrict__ bias,
                                                 const float* __restrict__ sArr,
                                                 const float* __restrict__ tArr,
                                                 const float* __restrict__ res,
                                                 float* __restrict__ out) {
  constexpr int DH = DD / HN;
  __shared__ float accL[4][16][65];
  __shared__ float msL[4][16][2];
  int t = threadIdx.x, w = t >> 6, l = t & 63;
  int li = l & 15, lg = l >> 4;
  int it = blockIdx.x;
  int ck = blockIdx.y;
  int bh = blockIdx.z;
  int h = bh % HN, b = bh / HN;
  int i0 = it * 16;
  int c0 = h * DH + ck * 64;
  int i = i0 + li;
  size_t bhN = (size_t)bh * NN;
  float si = sArr[bhN + i];
  const float* trow = tArr + bhN;
  const float* brow = bias + ((size_t)b * NN + i) * NN;
  const unsigned short* vb = hbT + ((size_t)b * DD + c0 + li) * NN + lg * 8;

  const int JW = NN / 4;
  const int jbeg = w * JW, jend = jbeg + JW;

  f32x4 acc[4] = {};
  float msum = 0.f, mrun = -1e30f;

  // 1-deep register prefetch of t, bias, V
  float4 nt0, nt1, nb0, nb1;
  short8 nv0, nv1, nv2, nv3;
  {
    int jb = jbeg + lg * 8;
    nt0 = *(const float4*)&trow[jb];
    nt1 = *(const float4*)&trow[jb + 4];
    nb0 = *(const float4*)&brow[jb];
    nb1 = *(const float4*)&brow[jb + 4];
    nv0 = *(const short8*)(vb + jbeg);
    nv1 = *(const short8*)(vb + (size_t)16 * NN + jbeg);
    nv2 = *(const short8*)(vb + (size_t)32 * NN + jbeg);
    nv3 = *(const short8*)(vb + (size_t)48 * NN + jbeg);
  }
  for (int j0 = jbeg; j0 < jend; j0 += 32) {
    float4 t0 = nt0, t1 = nt1, bb0 = nb0, bb1 = nb1;
    short8 vf0 = nv0, vf1 = nv1, vf2 = nv2, vf3 = nv3;
    if (j0 + 32 < jend) {
      int jb = j0 + 32 + lg * 8;
      nt0 = *(const float4*)&trow[jb];
      nt1 = *(const float4*)&trow[jb + 4];
      nb0 = *(const float4*)&brow[jb];
      nb1 = *(const float4*)&brow[jb + 4];
      nv0 = *(const short8*)(vb + j0 + 32);
      nv1 = *(const short8*)(vb + (size_t)16 * NN + j0 + 32);
      nv2 = *(const short8*)(vb + (size_t)32 * NN + j0 + 32);
      nv3 = *(const short8*)(vb + (size_t)48 * NN + j0 + 32);
    }
    float e[8];
    e[0] = si + t0.x; e[1] = si + t0.y; e[2] = si + t0.z; e[3] = si + t0.w;
    e[4] = si + t1.x; e[5] = si + t1.y; e[6] = si + t1.z; e[7] = si + t1.w;
#pragma unroll
    for (int k = 0; k < 8; k++) e[k] = fmaxf(e[k], 0.2f * e[k]);  // leaky relu
    e[0] += bb0.x; e[1] += bb0.y; e[2] += bb0.z; e[3] += bb0.w;
    e[4] += bb1.x; e[5] += bb1.y; e[6] += bb1.z; e[7] += bb1.w;
    float tm = fmaxf(fmaxf(fmaxf(e[0], e[1]), fmaxf(e[2], e[3])),
                     fmaxf(fmaxf(e[4], e[5]), fmaxf(e[6], e[7])));
    tm = fmaxf(tm, __shfl_xor(tm, 16));
    tm = fmaxf(tm, __shfl_xor(tm, 32));  // row-tile max (uniform per row group)
    if (!__all(tm - mrun <= 8.0f)) {
      float mnew = fmaxf(mrun, tm);
      float sc = __expf(mrun - mnew);  // first tile: exp(-inf)=0 zeroes state
      msum *= sc;
      mrun = mnew;
      float s0 = __shfl(sc, lg * 4 + 0);
      float s1 = __shfl(sc, lg * 4 + 1);
      float s2 = __shfl(sc, lg * 4 + 2);
      float s3 = __shfl(sc, lg * 4 + 3);
#pragma unroll
      for (int f = 0; f < 4; f++) {
        acc[f][0] *= s0; acc[f][1] *= s1; acc[f][2] *= s2; acc[f][3] *= s3;
      }
    }
    union { short8 v; unsigned short u[8]; } a;
    float lsum = 0.f;
#pragma unroll
    for (int k = 0; k < 8; k++) {
      float p = __expf(e[k] - mrun);
      lsum += p;
      a.u[k] = f2bf(p);
    }
    msum += lsum;
    acc[0] = __builtin_amdgcn_mfma_f32_16x16x32_bf16(a.v, vf0, acc[0], 0, 0, 0);
    acc[1] = __builtin_amdgcn_mfma_f32_16x16x32_bf16(a.v, vf1, acc[1], 0, 0, 0);
    acc[2] = __builtin_amdgcn_mfma_f32_16x16x32_bf16(a.v, vf2, acc[2], 0, 0, 0);
    acc[3] = __builtin_amdgcn_mfma_f32_16x16x32_bf16(a.v, vf3, acc[3], 0, 0, 0);
  }
  // per-wave row totals
  float srow = msum + __shfl_xor(msum, 16);
  srow += __shfl_xor(srow, 32);
  if (l < 16) {
    msL[w][li][0] = mrun;
    msL[w][li][1] = srow;
  }
#pragma unroll
  for (int f = 0; f < 4; f++)
#pragma unroll
    for (int r = 0; r < 4; r++) accL[w][lg * 4 + r][f * 16 + li] = acc[f][r];
  __syncthreads();
  // block merge: 256 threads cover 16 rows x 16 col-quads
  int r = t >> 4, cq = t & 15;
  float m = fmaxf(fmaxf(msL[0][r][0], msL[1][r][0]), fmaxf(msL[2][r][0], msL[3][r][0]));
  float S = 0.f;
  float4 O = {0.f, 0.f, 0.f, 0.f};
#pragma unroll
  for (int w2 = 0; w2 < 4; w2++) {
    float f = __expf(msL[w2][r][0] - m);
    S += f * msL[w2][r][1];
    O.x += f * accL[w2][r][cq * 4 + 0];
    O.y += f * accL[w2][r][cq * 4 + 1];
    O.z += f * accL[w2][r][cq * 4 + 2];
    O.w += f * accL[w2][r][cq * 4 + 3];
  }
  float inv = 1.0f / S;
  size_t ix = ((size_t)b * NN + i0 + r) * DD + c0 + cq * 4;
  float4 rv = *(const float4*)&res[ix];
  float4 ov;
  ov.x = O.x * inv + rv.x;
  ov.y = O.y * inv + rv.y;
  ov.z = O.z * inv + rv.z;
  ov.w = O.w * inv + rv.w;
  *(float4*)&out[ix] = ov;
}

extern "C" void kernel_launch(void* const* d_in, const int* in_sizes, int n_in,
                              void* d_out, int out_size, void* d_ws, size_t ws_size,
                              hipStream_t stream) {
  const float* x = (const float*)d_in[0];
  const float* bias = (const float*)d_in[1];
  const float* W1 = (const float*)d_in[2];
  const float* asrc1 = (const float*)d_in[3];
  const float* adst1 = (const float*)d_in[4];
  const float* g1 = (const float*)d_in[5];
  const float* b1 = (const float*)d_in[6];
  const float* W2 = (const float*)d_in[7];
  const float* asrc2 = (const float*)d_in[8];
  const float* adst2 = (const float*)d_in[9];
  const float* g2 = (const float*)d_in[10];
  const float* b2 = (const float*)d_in[11];
  float* out = (float*)d_out;
  float* ws = (float*)d_ws;

  const size_t RC = (size_t)NB * NN * DD;  // 2097152
  float* attnBuf = ws;                                        // 8 MB fp32
  unsigned short* lnB = (unsigned short*)(ws + RC);           // 4 MB bf16
  unsigned short* hbT = (unsigned short*)(ws + RC + RC / 2);  // 4 MB bf16
  unsigned short* WT1 = (unsigned short*)(ws + 2 * RC);       // 0.5 MB
  unsigned short* WT2 = WT1 + (size_t)DD * DD;                // 0.5 MB
  float* vs1 = (float*)(WT2 + (size_t)DD * DD);               // [8][512]
  float* vd1 = vs1 + 8 * DD;
  float* vs2 = vd1 + 8 * DD;  // [1][512]
  float* vd2 = vs2 + DD;
  float* sBuf = vd2 + DD;  // [16][2048]
  float* tBuf = sBuf + 16 * NN;

  const int rows = NB * NN;  // 4096

  // ---- input prep (no deps on x) ----
  hipLaunchKernelGGL(wt_kernel, dim3(8, 8), dim3(256), 0, stream, W1, WT1);
  hipLaunchKernelGGL(wt_kernel, dim3(8, 8), dim3(256), 0, stream, W2, WT2);
  hipLaunchKernelGGL(v_kernel, dim3(8), dim3(256), 0, stream, W1, asrc1, adst1, vs1, vd1, 8, 64);
  hipLaunchKernelGGL(v_kernel, dim3(8), dim3(256), 0, stream, W2, asrc2, adst2, vs2, vd2, 1, 512);

  // ---- layer 1 (H=8, Dh=64) ----
  hipLaunchKernelGGL(ln_kernel, dim3(rows), dim3(256), 0, stream, x, g1, b1, lnB);
  hipLaunchKernelGGL(gemm_kernel, dim3(256, 8), dim3(256), 0, stream, lnB, WT1, hbT);
  hipLaunchKernelGGL(st_kernel, dim3(rows / 4), dim3(256), 0, stream, lnB, vs1, vd1, sBuf, tBuf, 8);
  hipLaunchKernelGGL(pv_kernel<8>, dim3(128, 1, 16), dim3(256), 0, stream, hbT, bias, sBuf, tBuf,
                     x, attnBuf);

  // ---- layer 2 (H=1, Dh=512) ----
  hipLaunchKernelGGL(ln_kernel, dim3(rows), dim3(256), 0, stream, attnBuf, g2, b2, lnB);
  hipLaunchKernelGGL(gemm_kernel, dim3(256, 8), dim3(256), 0, stream, lnB, WT2, hbT);
  hipLaunchKernelGGL(st_kernel, dim3(rows / 4), dim3(256), 0, stream, lnB, vs2, vd2, sBuf, tBuf, 1);
  hipLaunchKernelGGL(pv_kernel<1>, dim3(128, 8, 2), dim3(256), 0, stream, hbT, bias, sBuf, tBuf,
                     attnBuf, out);
}